// Round 6
// baseline (308.573 us; speedup 1.0000x reference)
//
#include <hip/hip_runtime.h>
#include <hip/hip_bf16.h>
#include <math.h>

#define ROWLEN 901
#define NEGENC 0x007FFFFFu   // enc(-inf)
#define GSH 6                // 64 nodes per bin
#define G (1 << GSH)
#define MAXBINS 1024         // supports N <= 65536 (N = 50000 here)
#define NB_A 128             // phase-A binning blocks
#define SUB 32               // slots per (block, bin): Poisson(8) tail-safe
#define BINCAP (NB_A * SUB)  // 4096 entries per bin
#define ZB 96                // zero-role blocks in compose
#define SSTRIDE 5            // sMax stride: (5*dl+c)%32 uniform -> no bank conflicts

__device__ __forceinline__ unsigned encf(float f) {
    unsigned u = __float_as_uint(f);
    return (u & 0x80000000u) ? ~u : (u | 0x80000000u);
}
__device__ __forceinline__ float decf(unsigned u) {
    return (u & 0x80000000u) ? __uint_as_float(u ^ 0x80000000u)
                             : __uint_as_float(~u);
}

// ---------------------------------------------------------------------------
// K0: compose all linear algebra into small tables + zero counts/spillcnt.
//   blocks 0..15   : C[256][4] (16 rows/block, 16 threads/row, shfl reduce)
//   block 16       : sUV -> Tab[2][3][4], Sp[2][4][4], Cst[2][4]
//   blocks 17..    : zero counts[NB_A][nbins] + spillcnt
// ---------------------------------------------------------------------------
__global__ __launch_bounds__(256) void k_compose(
    const float* __restrict__ spkw, const float* __restrict__ spkb,
    const float* __restrict__ spaw, const float* __restrict__ spab,
    const float* __restrict__ f1w, const float* __restrict__ f1b,
    const float* __restrict__ f2w, const float* __restrict__ f2b,
    const float* __restrict__ few, const float* __restrict__ feb,
    const float* __restrict__ g1w, const float* __restrict__ g1b,
    const float* __restrict__ g2w, const float* __restrict__ g2b,
    const float* __restrict__ gew, const float* __restrict__ geb,
    float* __restrict__ C, float* __restrict__ Sp,
    float* __restrict__ Tab, float* __restrict__ Cst,
    uint4* __restrict__ zq, int nZeroQuads, int* __restrict__ spillcnt)
{
    const int t = threadIdx.x;

    if (blockIdx.x >= 17) {   // ---- zero role ----
        const int zid = blockIdx.x - 17;
        if (zid == 0 && t == 0) *spillcnt = 0;
        const uint4 z = make_uint4(0u, 0u, 0u, 0u);
        for (int i = zid * 256 + t; i < nZeroQuads; i += ZB * 256)
            zq[i] = z;
        return;
    }

    if (blockIdx.x < 16) {
        // ---- C rows: row = blockIdx*16 + (t>>4); thread covers k = (t&15)*4..+3
        const int row = blockIdx.x * 16 + (t >> 4);
        const int kk  = t & 15;
        const int blk = row >> 7;
        const int fr  = row & 127;
        const float* w1 = blk ? g1w : f1w;
        const float* w2 = blk ? g2w : f2w;
        const float* e  = blk ? gew : few;

        const float4 wa = *(const float4*)(w1 + fr * 64 + kk * 4);
        const float4 wb = *(const float4*)(w2 + fr * 64 + kk * 4);
        const float wv[4] = {wa.x + wb.x, wa.y + wb.y, wa.z + wb.z, wa.w + wb.w};

        float a0 = 0.f, a1 = 0.f, a2 = 0.f, a3 = 0.f;
        #pragma unroll
        for (int j = 0; j < 4; ++j) {
            const int k = kk * 4 + j;
            const float eb0 = e[(64 + k) * 2 + 0];
            const float eb1 = e[(64 + k) * 2 + 1];
            const float ea0 = e[k * 2 + 0] - eb0;
            const float ea1 = e[k * 2 + 1] - eb1;
            a0 += wv[j] * ea0; a1 += wv[j] * ea1;
            a2 += wv[j] * eb0; a3 += wv[j] * eb1;
        }
        #pragma unroll
        for (int m = 1; m <= 8; m <<= 1) {
            a0 += __shfl_xor(a0, m, 64);
            a1 += __shfl_xor(a1, m, 64);
            a2 += __shfl_xor(a2, m, 64);
            a3 += __shfl_xor(a3, m, 64);
        }
        if (kk == 0) {
            C[row * 4 + 0] = a0; C[row * 4 + 1] = a1;
            C[row * 4 + 2] = a2; C[row * 4 + 3] = a3;
        }
        return;
    }

    // ---- block 16: small tails ----
    __shared__ float sEW[2][256];
    __shared__ float sUV[2][2][2][16][2];  // [isV][blk][role][k16][c]
    __shared__ float sBE[8][8];

    sEW[0][t] = few[t];
    sEW[1][t] = gew[t];
    __syncthreads();

    {   // sUV: 16x2 per (isV, blk, role)
        const int c    = t & 1;
        const int k16  = (t >> 1) & 15;
        const int role = (t >> 5) & 1;
        const int blk  = (t >> 6) & 1;
        const int isV  = (t >> 7) & 1;
        const float* w2 = blk ? g2w : f2w;
        const float* e  = sEW[blk];
        const int row = (isV ? 144 : 128) + k16;
        float acc = 0.f;
        #pragma unroll
        for (int k4 = 0; k4 < 16; ++k4) {
            const float4 w = *(const float4*)(w2 + row * 64 + k4 * 4);
            const float wv[4] = {w.x, w.y, w.z, w.w};
            #pragma unroll
            for (int j = 0; j < 4; ++j) {
                const int k = k4 * 4 + j;
                const float ev = role ? e[(64 + k) * 2 + c]
                                      : (e[k * 2 + c] - e[(64 + k) * 2 + c]);
                acc += wv[j] * ev;
            }
        }
        sUV[isV][blk][role][k16][c] = acc;
    }

    if (t < 64) {  // sBE partials: (b1+b2)·e split 8 ways per combo
        const int combo = t >> 3;            // blk<<2 | role<<1 | c
        const int part  = t & 7;
        const int c = combo & 1, role = (combo >> 1) & 1, blk = combo >> 2;
        const float* b1 = blk ? g1b : f1b;
        const float* b2 = blk ? g2b : f2b;
        const float* e  = sEW[blk];
        float acc = 0.f;
        #pragma unroll
        for (int j = 0; j < 8; ++j) {
            const int k = part * 8 + j;
            const float ev = role ? e[(64 + k) * 2 + c]
                                  : (e[k * 2 + c] - e[(64 + k) * 2 + c]);
            acc += (b1[k] + b2[k]) * ev;
        }
        sBE[combo][part] = acc;
    }
    __syncthreads();

    if (t < 24) {  // Tab
        const int blk = t / 12, rem = t % 12;
        const int idx = rem >> 2, q = rem & 3;
        const int role = q >> 1, c = q & 1;
        float acc = 0.f;
        #pragma unroll
        for (int k = 0; k < 16; ++k)
            acc += spkw[idx * 16 + k] * sUV[0][blk][role][k][c];
        Tab[blk * 12 + idx * 4 + q] = acc;
    } else if (t >= 32 && t < 64) {  // Sp
        const int u = t - 32;
        const int blk = u >> 4, rem = u & 15;
        const int r = rem >> 2, q = rem & 3;
        const int role = q >> 1, c = q & 1;
        float acc = 0.f;
        #pragma unroll
        for (int k = 0; k < 16; ++k)
            acc += spaw[r * 16 + k] * sUV[1][blk][role][k][c];
        Sp[blk * 16 + r * 4 + q] = acc;
    } else if (t >= 64 && t < 72) {  // Cst
        const int u = t - 64;
        const int blk = u >> 2, q = u & 3;
        const int role = q >> 1, c = q & 1;
        const float* ebv = blk ? geb : feb;
        float acc = (role == 0) ? ebv[c] : 0.f;
        #pragma unroll
        for (int k = 0; k < 16; ++k) {
            acc += spkb[k] * sUV[0][blk][role][k][c];
            acc += spab[k] * sUV[1][blk][role][k][c];
        }
        #pragma unroll
        for (int p = 0; p < 8; ++p) acc += sBE[u][p];
        Cst[blk * 4 + q] = acc;
    }
}

// ---------------------------------------------------------------------------
// K1 fused:
//   blocks [0, NB_A)  : phase-A edge binning — LDS counters, deterministic
//                       per-(block,bin) slices, ZERO global atomics hot path.
//                       entry = src | (dst&63)<<20  (4B; needs N <= 2^20)
//   blocks [NB_A, ...) : per-node feature reduction. Lane reads x as ONE
//                       dwordx4 (wave = exactly the 1024B feature block).
// ---------------------------------------------------------------------------
__global__ __launch_bounds__(256) void k_fused(
    const float* __restrict__ x,
    const float* __restrict__ C, const float* __restrict__ Sp,
    const float* __restrict__ Tab, const float* __restrict__ Cst,
    float4* __restrict__ Adat, float4* __restrict__ Bdat, int nnodes,
    const int* __restrict__ ei, const int* __restrict__ ea,
    int* __restrict__ binData, int* __restrict__ counts,
    int* __restrict__ spillcnt, int* __restrict__ spill,
    int nedges, int nbins)
{
    __shared__ int sCnt[MAXBINS];

    if (blockIdx.x < NB_A) {
        // ---------------- phase-A binning role ----------------
        for (int i = threadIdx.x; i < nbins; i += 256) sCnt[i] = 0;
        __syncthreads();
        const int chunk = (nedges + NB_A - 1) / NB_A;
        const int e0 = blockIdx.x * chunk;
        const int e1 = min(e0 + chunk, nedges);
        for (int e = e0 + threadIdx.x; e < e1; e += 256) {
            const int attr = ea[e];
            if (!(attr == 0 || attr == 111)) continue;
            const int s = ei[e];
            const int d = ei[nedges + e];
            const int bin = d >> GSH;
            const int slot = atomicAdd(&sCnt[bin], 1);   // LDS atomic: cheap
            if (slot < SUB) {
                binData[(size_t)bin * BINCAP + blockIdx.x * SUB + slot] =
                    s | ((d & (G - 1)) << 20);
            } else {                                     // ~never (Poisson(8))
                const int sp = atomicAdd(spillcnt, 1);
                spill[2 * sp + 0] = d;
                spill[2 * sp + 1] = s;
            }
        }
        __syncthreads();
        for (int i = threadIdx.x; i < nbins; i += 256)
            counts[blockIdx.x * nbins + i] = sCnt[i];    // dense store
        return;
    }

    // ---------------- node role: one wave per node ----------------
    const int wave = threadIdx.x >> 6;
    const int lane = threadIdx.x & 63;
    const int node = (blockIdx.x - NB_A) * 4 + wave;
    if (node >= nnodes) return;

    const float* xr = x + (size_t)node * ROWLEN;
    const int half = lane >> 5;        // 0 face, 1 body
    const int l32  = lane & 31;
    const float4* C4 = (const float4*)C;

    float xs0 = 0.f, xs1 = 0.f, xs2 = 0.f, xs3 = 0.f, xspk = 0.f;
    if (lane == 0) {
        xs0 = xr[896]; xs1 = xr[897]; xs2 = xr[898]; xs3 = xr[899];
        xspk = xr[900];
    }

    // lane covers features f0..f0+3 (f0 = half*128 + l32*4): wave = 1024B block
    const int f0 = half * 128 + l32 * 4;
    const float4 xv = *(const float4*)(xr + f0);
    const float xvv[4] = {xv.x, xv.y, xv.z, xv.w};

    float a0 = 0.f, a1 = 0.f, a2 = 0.f, a3 = 0.f;
    #pragma unroll
    for (int j = 0; j < 4; ++j) {
        const float4 cr = C4[f0 + j];
        a0 += xvv[j] * cr.x; a1 += xvv[j] * cr.y;
        a2 += xvv[j] * cr.z; a3 += xvv[j] * cr.w;
    }

    #pragma unroll
    for (int m = 16; m >= 1; m >>= 1) {
        a0 += __shfl_xor(a0, m, 64);
        a1 += __shfl_xor(a1, m, 64);
        a2 += __shfl_xor(a2, m, 64);
        a3 += __shfl_xor(a3, m, 64);
    }
    const float b0 = __shfl(a0, 32, 64);
    const float b1 = __shfl(a1, 32, 64);
    const float b2 = __shfl(a2, 32, 64);
    const float b3 = __shfl(a3, 32, 64);

    if (lane == 0) {
        const float xs[4] = {xs0, xs1, xs2, xs3};
        int idx = (int)fminf(xspk - 1.0f, 2.0f);
        idx = idx < 0 ? 0 : (idx > 2 ? 2 : idx);

        const float pq[2][4] = {{a0, a1, a2, a3}, {b0, b1, b2, b3}};
        float av[4], bv[4];
        #pragma unroll
        for (int blk = 0; blk < 2; ++blk) {
            #pragma unroll
            for (int c = 0; c < 2; ++c) {
                float ea_ = Tab[blk * 12 + idx * 4 + c] + Cst[blk * 4 + c];
                float eb_ = Tab[blk * 12 + idx * 4 + 2 + c] + Cst[blk * 4 + 2 + c];
                #pragma unroll
                for (int r = 0; r < 4; ++r) {
                    ea_ += xs[r] * Sp[blk * 16 + r * 4 + c];
                    eb_ += xs[r] * Sp[blk * 16 + r * 4 + 2 + c];
                }
                av[blk * 2 + c] = pq[blk][c] + ea_;
                bv[blk * 2 + c] = pq[blk][2 + c] + eb_;
            }
        }
        Adat[node] = make_float4(av[0], av[1], av[2], av[3]);
        Bdat[node] = make_float4(bv[0], bv[1], bv[2], bv[3]);
    }
}

// ---------------------------------------------------------------------------
// K2: one block per bin (64 dst nodes). Max Bdat[src] over the bin's entries
// into LDS (encoded-uint atomicMax, STRIDE-5 layout -> conflict-free banks),
// fold spill (~never) + Adat, write out.
// ---------------------------------------------------------------------------
__global__ __launch_bounds__(256) void k_final(
    const float4* __restrict__ Adat, const float4* __restrict__ Bdat,
    const int* __restrict__ binData, const int* __restrict__ counts,
    const int* __restrict__ spillcnt, const int* __restrict__ spill,
    float* __restrict__ out, int nnodes, int nbins)
{
    const int bin = blockIdx.x;
    const int t = threadIdx.x;
    __shared__ unsigned sMax[G * SSTRIDE];
    __shared__ int sC[NB_A];
    __shared__ int sNs;

    for (int i = t; i < G * SSTRIDE; i += 256) sMax[i] = NEGENC;
    if (t < NB_A) sC[t] = counts[t * nbins + bin];
    if (t == 0) sNs = *spillcnt;
    __syncthreads();

    // NB_A slices; 32 slices per round x 8 threads each
    #pragma unroll
    for (int r = 0; r < NB_A / 32; ++r) {
        const int slice = r * 32 + (t >> 3);
        int c = sC[slice]; if (c > SUB) c = SUB;
        const int* base = binData + (size_t)bin * BINCAP + slice * SUB;
        for (int j = (t & 7); j < c; j += 8) {
            const int entry = base[j];
            const int s  = entry & 0xFFFFF;
            const int dl = (entry >> 20) & (G - 1);
            const float4 b = Bdat[s];                    // L2/L3-resident
            atomicMax(&sMax[dl * SSTRIDE + 0], encf(b.x));
            atomicMax(&sMax[dl * SSTRIDE + 1], encf(b.y));
            atomicMax(&sMax[dl * SSTRIDE + 2], encf(b.z));
            atomicMax(&sMax[dl * SSTRIDE + 3], encf(b.w));
        }
    }

    if (sNs > 0) {   // rare overflow path
        const int lo = bin << GSH, hi = lo + G;
        for (int j = t; j < sNs; j += 256) {
            const int d = spill[2 * j];
            if (d >= lo && d < hi) {
                const float4 b = Bdat[spill[2 * j + 1]];
                const int dl = d - lo;
                atomicMax(&sMax[dl * SSTRIDE + 0], encf(b.x));
                atomicMax(&sMax[dl * SSTRIDE + 1], encf(b.y));
                atomicMax(&sMax[dl * SSTRIDE + 2], encf(b.z));
                atomicMax(&sMax[dl * SSTRIDE + 3], encf(b.w));
            }
        }
    }
    __syncthreads();

    if (t < G) {
        const int n = (bin << GSH) + t;
        if (n < nnodes) {
            const float m0 = decf(sMax[t * SSTRIDE + 0]);
            const float m1 = decf(sMax[t * SSTRIDE + 1]);
            const float m2 = decf(sMax[t * SSTRIDE + 2]);
            const float m3 = decf(sMax[t * SSTRIDE + 3]);
            const float4 a = Adat[n];
            const float f0 = isfinite(m0) ? a.x + m0 : 0.f;
            const float f1 = isfinite(m1) ? a.y + m1 : 0.f;
            const float f2 = isfinite(m2) ? a.z + m2 : 0.f;
            const float f3 = isfinite(m3) ? a.w + m3 : 0.f;
            out[(size_t)n * 2 + 0] = f0 + f2;
            out[(size_t)n * 2 + 1] = f1 + f3;
        }
    }
}

extern "C" void kernel_launch(void* const* d_in, const int* in_sizes, int n_in,
                              void* d_out, int out_size, void* d_ws, size_t ws_size,
                              hipStream_t stream) {
    const float* x    = (const float*)d_in[0];
    const int*   ei   = (const int*)d_in[1];
    const int*   ea   = (const int*)d_in[2];
    const float* spkw = (const float*)d_in[3];
    const float* spkb = (const float*)d_in[4];
    const float* spaw = (const float*)d_in[5];
    const float* spab = (const float*)d_in[6];
    const float* f1w  = (const float*)d_in[7];
    const float* f1b  = (const float*)d_in[8];
    const float* f2w  = (const float*)d_in[9];
    const float* f2b  = (const float*)d_in[10];
    const float* few  = (const float*)d_in[11];
    const float* feb  = (const float*)d_in[12];
    const float* g1w  = (const float*)d_in[13];
    const float* g1b  = (const float*)d_in[14];
    const float* g2w  = (const float*)d_in[15];
    const float* g2b  = (const float*)d_in[16];
    const float* gew  = (const float*)d_in[17];
    const float* geb  = (const float*)d_in[18];

    const int N = in_sizes[0] / ROWLEN;
    const int E = in_sizes[2];
    const int nbins = (N + G - 1) >> GSH;   // 782 for N=50000 (<= MAXBINS)

    // workspace layout
    char* ws = (char*)d_ws;
    float*    C      = (float*)(ws + 0);
    float*    Sp     = (float*)(ws + 4096);
    float*    Tab    = (float*)(ws + 4096 + 128);
    float*    Cst    = (float*)(ws + 4096 + 256);
    size_t off = 16384;
    float4*   Adat   = (float4*)(ws + off);   off += (size_t)N * 16;
    float4*   Bdat   = (float4*)(ws + off);   off += (size_t)N * 16;
    size_t countsBytes = (((size_t)NB_A * nbins * 4 + 255) / 256) * 256;
    int*      counts = (int*)(ws + off);      off += countsBytes;
    int*      spillcnt = (int*)(ws + off);    off += 256;
    int*      spill  = (int*)(ws + off);      off += (((size_t)E * 8 + 255) / 256) * 256;
    int*      binData = (int*)(ws + off);     // nbins * BINCAP * 4 bytes (~12.5 MB)

    const int nZeroQuads = (int)(countsBytes / 16);

    k_compose<<<17 + ZB, 256, 0, stream>>>(spkw, spkb, spaw, spab,
                                           f1w, f1b, f2w, f2b, few, feb,
                                           g1w, g1b, g2w, g2b, gew, geb,
                                           C, Sp, Tab, Cst,
                                           (uint4*)counts, nZeroQuads, spillcnt);

    const int NB_ND = (N + 3) / 4;
    k_fused<<<NB_A + NB_ND, 256, 0, stream>>>(x, C, Sp, Tab, Cst,
                                              Adat, Bdat, N,
                                              ei, ea, binData, counts,
                                              spillcnt, spill, E, nbins);

    k_final<<<nbins, 256, 0, stream>>>(Adat, Bdat, binData, counts,
                                       spillcnt, spill,
                                       (float*)d_out, N, nbins);
}